// Round 5
// baseline (1198.628 us; speedup 1.0000x reference)
//
#include <hip/hip_runtime.h>
#include <cstdint>

// Instant-NGP hash-grid encoder, D=3, L=16, C=2, H=16, PS=2, T=2^19.
// Round-7: inline-asm depth-8 pipeline for the transpose.
//   r6 result: pair-merge cut gather 920->833us (request-rate component
//   confirmed); gather now near its floor (lines/point irreducible).
//   Transpose stuck at 337-358us (1.59 TB/s for 536MB coalesced streaming)
//   across 4 implementations -> compiler serializes load->ds_write per
//   element (same IR sinking that defeated r1-r5 pins). Escalation per r2
//   pre-commit: loads in raw asm volatile global_load_dwordx4 (opaque,
//   cannot be sunk), LDS writes fenced by hand-counted
//   "s_waitcnt vmcnt(7-k)" memory-clobber asms -> true depth-8 per wave.
//   New LDS layout: level-major linear, 516-float (2064B) level stride:
//   bank rotation 4/level => phase-1 writes sequential (conflict-free),
//   phase-2 paired ds_read_b64 exactly 2-way (free, m136).
//   This is also the decisive probe for the CU concurrency pool: if
//   transpose jumps to ~5-6 TB/s, port asm-depth to gather next; if it
//   stays ~330us the pool is shallow => both kernels at the same HW wall.
// Gather kernel: byte-identical to r6 (clean attribution).
// NUMERICS: pos = x01*scale + 0.5 must be two separately-rounded f32 ops
// (numpy semantics); __fmul_rn/__fadd_rn block FMA contraction there.

typedef float f2 __attribute__((ext_vector_type(2)));
typedef float f4 __attribute__((ext_vector_type(4)));
typedef float f4a8 __attribute__((ext_vector_type(4), aligned(8)));

static constexpr uint32_t PRIME1 = 2654435761u;
static constexpr uint32_t PRIME2 = 805459861u;
static constexpr uint32_t HASH_MASK = (1u << 19) - 1u;

__constant__ uint32_t c_offs[16] = {
    0u, 4920u, 40864u, 315496u, 839784u, 1364072u, 1888360u, 2412648u,
    2936936u, 3461224u, 3985512u, 4509800u, 5034088u, 5558376u,
    6082664u, 6606952u};

__global__ __launch_bounds__(256) void gather_kernel(
    const float* __restrict__ inputs,      // [B,3]
    const float* __restrict__ embeddings,  // [4920,2] (level-0 rows)
    const float* __restrict__ table,       // [TOTAL-4920,2]
    float2* __restrict__ dst,              // staged: ws[l*B + b] ; direct: out_f2[b*16 + l]
    int B, int chunks, int directOut)
{
    // --- block -> (level, chunk) with XCD pinning ---
    const int j   = blockIdx.x;
    const int xcd = j & 7;
    const int s   = j >> 3;
    const int lvl = 2 * xcd + (s >= chunks ? 1 : 0);
    const int chunk = (s >= chunks) ? (s - chunks) : s;
    const int base  = chunk * 1024;           // 4 points/thread * 256 threads
    const int tid   = threadIdx.x;

    // --- stage this chunk's inputs through LDS (coalesced, nontemporal) ---
    __shared__ float sIn[3072];
    {
        const float* gp = inputs + (size_t)base * 3;
        const int lim = B * 3 - base * 3;
#pragma unroll
        for (int k = 0; k < 12; ++k) {
            const int i = tid + k * 256;
            sIn[i] = (i < lim) ? __builtin_nontemporal_load(gp + i) : 0.0f;
        }
    }
    __syncthreads();

    // --- level-dependent constants (block-uniform) ---
    const float scale = (float)((16u << lvl) - 1u);   // exactly representable
    const uint32_t off = c_offs[lvl];
    const f2* __restrict__ tb = (lvl == 0)
        ? (const f2*)embeddings
        : ((const f2*)table) + (off - 4920u);
    const float* __restrict__ tbf = (const float*)tb;
    const bool dense = (lvl < 3);
    const uint32_t dstr  = (16u << lvl) + 1u;   // dense row stride
    const uint32_t dstr2 = dstr * dstr;

    f2 e[4][8];
    float fx[4], fy[4], fz[4];

#pragma unroll
    for (int p = 0; p < 4; ++p) {
        const int li = p * 256 + tid;           // local point index
        // bound=1: x01=(x+1)/2 (add rounds once, *0.5 exact)
        const float x01 = __fadd_rn(sIn[li * 3 + 0], 1.0f) * 0.5f;
        const float y01 = __fadd_rn(sIn[li * 3 + 1], 1.0f) * 0.5f;
        const float z01 = __fadd_rn(sIn[li * 3 + 2], 1.0f) * 0.5f;

        // pos = x01*scale + 0.5 : two separately-rounded ops (NO fma)
        const float px = __fadd_rn(__fmul_rn(x01, scale), 0.5f);
        const float py = __fadd_rn(__fmul_rn(y01, scale), 0.5f);
        const float pz = __fadd_rn(__fmul_rn(z01, scale), 0.5f);

        const float fxf = floorf(px), fyf = floorf(py), fzf = floorf(pz);
        fx[p] = px - fxf;  fy[p] = py - fyf;  fz[p] = pz - fzf;   // exact
        const uint32_t ix = (uint32_t)fxf, iy = (uint32_t)fyf, iz = (uint32_t)fzf;

        if (dense) {
            // pairs {i, i+1} always adjacent -> one dwordx4 each (8B-aligned)
            const uint32_t oy0 = iy * dstr,  oy1 = oy0 + dstr;
            const uint32_t oz0 = iz * dstr2, oz1 = oz0 + dstr2;
            const uint32_t i0 = ix + oy0 + oz0, i2 = ix + oy1 + oz0;
            const uint32_t i4 = ix + oy0 + oz1, i6 = ix + oy1 + oz1;
            f4 t0 = *(const f4a8*)(tbf + 2u * i0);
            f4 t2 = *(const f4a8*)(tbf + 2u * i2);
            f4 t4 = *(const f4a8*)(tbf + 2u * i4);
            f4 t6 = *(const f4a8*)(tbf + 2u * i6);
            e[p][0] = (f2){t0.x, t0.y}; e[p][1] = (f2){t0.z, t0.w};
            e[p][2] = (f2){t2.x, t2.y}; e[p][3] = (f2){t2.z, t2.w};
            e[p][4] = (f2){t4.x, t4.y}; e[p][5] = (f2){t4.z, t4.w};
            e[p][6] = (f2){t6.x, t6.y}; e[p][7] = (f2){t6.z, t6.w};
        } else {
            const uint32_t hy0 = iy * PRIME1, hy1 = hy0 + PRIME1;  // u32 wrap
            const uint32_t hz0 = iz * PRIME2, hz1 = hz0 + PRIME2;
            const uint32_t a00 = hy0 ^ hz0, a10 = hy1 ^ hz0;
            const uint32_t a01 = hy0 ^ hz1, a11 = hy1 ^ hz1;
            if (!(ix & 1u)) {
                // ix even: ix+1 = ix|1, so pair = {v, v^1} = aligned 16B cell
                const uint32_t v0 = (ix ^ a00) & HASH_MASK;
                const uint32_t v2 = (ix ^ a10) & HASH_MASK;
                const uint32_t v4 = (ix ^ a01) & HASH_MASK;
                const uint32_t v6 = (ix ^ a11) & HASH_MASK;
                f4 t0 = *(const f4a8*)(tbf + 2u * (v0 & ~1u));
                f4 t2 = *(const f4a8*)(tbf + 2u * (v2 & ~1u));
                f4 t4 = *(const f4a8*)(tbf + 2u * (v4 & ~1u));
                f4 t6 = *(const f4a8*)(tbf + 2u * (v6 & ~1u));
                // route halves by parity of the c0 index
                e[p][0] = (v0 & 1u) ? (f2){t0.z, t0.w} : (f2){t0.x, t0.y};
                e[p][1] = (v0 & 1u) ? (f2){t0.x, t0.y} : (f2){t0.z, t0.w};
                e[p][2] = (v2 & 1u) ? (f2){t2.z, t2.w} : (f2){t2.x, t2.y};
                e[p][3] = (v2 & 1u) ? (f2){t2.x, t2.y} : (f2){t2.z, t2.w};
                e[p][4] = (v4 & 1u) ? (f2){t4.z, t4.w} : (f2){t4.x, t4.y};
                e[p][5] = (v4 & 1u) ? (f2){t4.x, t4.y} : (f2){t4.z, t4.w};
                e[p][6] = (v6 & 1u) ? (f2){t6.z, t6.w} : (f2){t6.x, t6.y};
                e[p][7] = (v6 & 1u) ? (f2){t6.x, t6.y} : (f2){t6.z, t6.w};
            } else {
                // ix odd: ix+1 carries -> second corner is far; 8 separate loads
                const uint32_t ixp = ix + 1u;
                e[p][0] = tb[(ix  ^ a00) & HASH_MASK];
                e[p][1] = tb[(ixp ^ a00) & HASH_MASK];
                e[p][2] = tb[(ix  ^ a10) & HASH_MASK];
                e[p][3] = tb[(ixp ^ a10) & HASH_MASK];
                e[p][4] = tb[(ix  ^ a01) & HASH_MASK];
                e[p][5] = tb[(ixp ^ a01) & HASH_MASK];
                e[p][6] = tb[(ix  ^ a11) & HASH_MASK];
                e[p][7] = tb[(ixp ^ a11) & HASH_MASK];
            }
        }
    }

    // --- weights + combine + write (unchanged arithmetic) ---
#pragma unroll
    for (int p = 0; p < 4; ++p) {
        const int b = base + p * 256 + tid;
        if (b >= B) continue;
        const float tx = fx[p], ty = fy[p], tz = fz[p];
        const float wx0 = 1.0f - tx, wy0 = 1.0f - ty, wz0 = 1.0f - tz;
        // ((x)*(y))*(z) product order matches jnp.prod
        const float wxy00 = __fmul_rn(wx0, wy0), wxy10 = __fmul_rn(tx, wy0);
        const float wxy01 = __fmul_rn(wx0, ty),  wxy11 = __fmul_rn(tx, ty);
        float w[8];
        w[0] = __fmul_rn(wxy00, wz0); w[1] = __fmul_rn(wxy10, wz0);
        w[2] = __fmul_rn(wxy01, wz0); w[3] = __fmul_rn(wxy11, wz0);
        w[4] = __fmul_rn(wxy00, tz);  w[5] = __fmul_rn(wxy10, tz);
        w[6] = __fmul_rn(wxy01, tz);  w[7] = __fmul_rn(wxy11, tz);

        float r0 = __fmul_rn(w[0], e[p][0].x);
        float r1 = __fmul_rn(w[0], e[p][0].y);
#pragma unroll
        for (int c = 1; c < 8; ++c) {
            r0 = fmaf(w[c], e[p][c].x, r0);
            r1 = fmaf(w[c], e[p][c].y, r1);
        }
        f2 res = {r0, r1};
        if (directOut) {
            __builtin_nontemporal_store(res, (f2*)&dst[(size_t)b * 16 + lvl]);
        } else {
            __builtin_nontemporal_store(res, (f2*)&dst[(size_t)lvl * B + b]);
        }
    }
}

// ws[16][B] float2 (level-major)  ->  out[B][32] float (point-major)
// Inline-asm depth-8 pipeline. LDS layout: level-major linear,
// 516-float (2064B) stride per level => bank rotation of 4 per level.
//   float index of (level l, point p): l*516 + (p>>1)*4 + (p&1)*2
// Phase 1: lane k-th load covers (l = (k*256+tid)>>7, pair q = idx&127):
//   16B from ws[l][b0+2q] -> sL[l*516 + q*4], ds_write_b128, sequential
//   within a wave (conflict-free).
// Phase 2: out chunk f = p*8+jj needs levels {2jj,2jj+1} of point p:
//   two ds_read_b64; banks = (4q + 2half + 8jj (+4)) mod 32 -> exactly
//   2 lanes/bank (free, m136).
__global__ __launch_bounds__(256) void transpose_kernel(
    const float2* __restrict__ ws, float* __restrict__ out, int B)
{
    __shared__ __align__(16) float sL[16 * 516];   // 33024 B -> 4 blocks/CU
    const int tid = threadIdx.x;
    const int b0  = blockIdx.x * 256;

    if (b0 + 256 <= B) {
        const f4* gp[8];
        int lo[8];
#pragma unroll
        for (int k = 0; k < 8; ++k) {
            const int idx = k * 256 + tid;
            const int l = idx >> 7, q = idx & 127;
            gp[k] = (const f4*)(ws + (size_t)l * B + b0 + 2 * q);
            lo[k] = l * 516 + q * 4;
        }
        // --- 8 loads issued back-to-back inside opaque asm (cannot be
        //     sunk by IR passes; no compiler-inserted waits) ---
        f4 t[8];
#pragma unroll
        for (int k = 0; k < 8; ++k)
            asm volatile("global_load_dwordx4 %0, %1, off"
                         : "=&v"(t[k]) : "v"(gp[k]));
        // --- drain one at a time with hand-counted vmcnt; each ds_write
        //     (C code, fenced by memory-clobber asms) only needs its own
        //     load complete -> 7..0 in flight throughout ---
#pragma unroll
        for (int k = 0; k < 8; ++k) {
            asm volatile("s_waitcnt vmcnt(%0)" :: "i"(7 - k) : "memory");
            *(f4*)&sL[lo[k]] = t[k];
        }
        __syncthreads();

        float* obase = out + (size_t)b0 * 32;
#pragma unroll
        for (int k = 0; k < 8; ++k) {
            const int f = k * 256 + tid;     // float4 chunk within tile
            const int p = f >> 3;            // point 0..255
            const int jj = f & 7;            // level-pair 0..7
            const int q = p >> 1, half = p & 1;
            const f2 u0 = *(const f2*)&sL[(2 * jj)     * 516 + q * 4 + half * 2];
            const f2 u1 = *(const f2*)&sL[(2 * jj + 1) * 516 + q * 4 + half * 2];
            f4 r = {u0.x, u0.y, u1.x, u1.y};
            __builtin_nontemporal_store(r, (f4*)(obase + (size_t)f * 4));
        }
    } else {
        // tail tile (unused for B = 2^21, kept for generality)
        for (int p = tid; p < B - b0; p += 256) {
            const int b = b0 + p;
#pragma unroll
            for (int l = 0; l < 16; ++l) {
                float2 u = ws[(size_t)l * B + b];
                out[(size_t)b * 32 + 2 * l]     = u.x;
                out[(size_t)b * 32 + 2 * l + 1] = u.y;
            }
        }
    }
}

extern "C" void kernel_launch(void* const* d_in, const int* in_sizes, int n_in,
                              void* d_out, int out_size, void* d_ws, size_t ws_size,
                              hipStream_t stream) {
    const float* inputs     = (const float*)d_in[0];
    const float* embeddings = (const float*)d_in[1];
    const float* table      = (const float*)d_in[2];
    float* out              = (float*)d_out;

    const int B = in_sizes[0] / 3;
    const int chunks = (B + 1023) / 1024;
    const size_t need = (size_t)16 * (size_t)B * sizeof(float2);
    const bool staged = ws_size >= need;

    gather_kernel<<<16 * chunks, 256, 0, stream>>>(
        inputs, embeddings, table,
        staged ? (float2*)d_ws : (float2*)d_out,
        B, chunks, staged ? 0 : 1);

    if (staged) {
        transpose_kernel<<<(B + 255) / 256, 256, 0, stream>>>(
            (const float2*)d_ws, out, B);
    }
}